// Round 5
// baseline (381.914 us; speedup 1.0000x reference)
//
#include <hip/hip_runtime.h>

#define Bsz 8
#define Nn  512
#define Dd  768
#define Ll  16

#define SPAN_BLOCKS 2048
#define PREP_BLOCKS (Bsz * (Nn / 8))   // 512

// ws layout (floats): At[65536] | Bt[65536] | se_part[512] | pb[SPAN_BLOCKS*8]
// pb[blk*8 + {0:tp,1:tn,2:fp,3:valc,4:span_loss_sum}]  -- plain stores, NO atomics

// ---------------------------------------------------------------------------
// Kernel 1: unchanged (proven).
// ---------------------------------------------------------------------------
__global__ __launch_bounds__(256) void k_prep(
    const float* __restrict__ x, const float* __restrict__ start,
    const float* __restrict__ end, const int* __restrict__ seqlen,
    const float* __restrict__ W_se, const float* __restrict__ b_se,
    const float* __restrict__ W_span, const float* __restrict__ b_span,
    float* __restrict__ At, float* __restrict__ Bt, float* __restrict__ se_part)
{
    __shared__ float xs[8 * Dd];        // 24 KB
    __shared__ float part[256 * 8];     // 8 KB
    __shared__ float s_se;

    const int tid = threadIdx.x;
    const int blk = blockIdx.x;         // 512 blocks: b*64 + group
    const int b   = blk >> 6;
    const int n0  = (blk & 63) * 8;

    if (tid == 0) s_se = 0.0f;

    const float4* xsrc = (const float4*)(x + (size_t)(b * Nn + n0) * Dd);
    float4* xd = (float4*)xs;
    for (int i = tid; i < 8 * Dd / 4; i += 256) xd[i] = xsrc[i];
    __syncthreads();

    const int c = tid & 63;   // column 0..63
    const int q = tid >> 6;   // k-quarter 0..3

    float a8[8];
#pragma unroll
    for (int r = 0; r < 8; ++r) a8[r] = 0.0f;

    const float* w;
    int stride;
    if (c < 32)       { w = W_se + c;                    stride = 32; }
    else if (c < 48)  { w = W_span + (c - 32);           stride = 16; }
    else              { w = W_span + Dd * 16 + (c - 48); stride = 16; }

    const int k0 = q * 192;
#pragma unroll 4
    for (int k = k0; k < k0 + 192; ++k) {
        const float wv = w[(size_t)k * stride];
#pragma unroll
        for (int r = 0; r < 8; ++r) a8[r] += xs[r * Dd + k] * wv;
    }
#pragma unroll
    for (int r = 0; r < 8; ++r) part[tid * 8 + r] = a8[r];
    __syncthreads();

    if (tid < 64) {
        float z[8];
#pragma unroll
        for (int r = 0; r < 8; ++r)
            z[r] = part[c * 8 + r] + part[(c + 64) * 8 + r] +
                   part[(c + 128) * 8 + r] + part[(c + 192) * 8 + r];

        if (c < 32) {
            const int sl = seqlen[b];
            float lsum = 0.0f;
            const float bse = b_se[c];
#pragma unroll
            for (int r = 0; r < 8; ++r) {
                const int n = n0 + r;
                const float zz = z[r] + bse;
                const float p = 1.0f / (1.0f + __expf(-zz));
                const float y = (c < 16) ? start[(b * Ll + c) * Nn + n]
                                         : end[(b * Ll + (c - 16)) * Nn + n];
                const float fl = (y == 1.0f)
                    ? (-0.5f * (1.0f - p) * (1.0f - p) * __logf(p))
                    : (-0.5f * p * p * __logf(1.0f - p));
                if (n < sl) lsum += fl;
            }
            atomicAdd(&s_se, lsum);
        } else if (c < 48) {
            const int l = c - 32;
            const float bsp = b_span[l];
#pragma unroll
            for (int r = 0; r < 8; ++r)
                At[(b * Ll + l) * Nn + n0 + r] = z[r] + bsp;  // bias folded in
        } else {
            const int l = c - 48;
#pragma unroll
            for (int r = 0; r < 8; ++r)
                Bt[(b * Ll + l) * Nn + n0 + r] = z[r];
        }
    }
    __syncthreads();
    if (tid == 0) se_part[blk] = s_se;
}

// ---------------------------------------------------------------------------
// Kernel 2a: k_stats — READ-ONLY pass. span+val (256 MB) -> per-block
// tp/tn/fp/valc/loss partials. No out stores: un-mixes the write stream
// from the read streams (H1 test). z recomputed from tiny L2-resident
// At/Bt, identical expression to k_pred so pred agrees.
//
// Indexing identities (verified): vid = blk*4096 + st*256 + tid;
//   ri = vid>>7 = (base0>>7) + 2*st  (st*256 is a multiple of 128)
//   Bt idx = ((vid>>16)<<9) | ((vid&127)<<2) — invariant per thread
// ---------------------------------------------------------------------------
__global__ __launch_bounds__(256) void k_stats(
    const float* __restrict__ At, const float* __restrict__ Bt,
    const int* __restrict__ span, const int* __restrict__ val,
    float* __restrict__ pb)
{
    const int tid = threadIdx.x;
    const int base0 = blockIdx.x * (256 * 16) + tid;   // float4-item index

    const int4* s4 = (const int4*)span;
    const int4* v4 = (const int4*)val;

    const float4 bt = *(const float4*)(Bt + ((base0 >> 16) << 9) + ((base0 & 127) << 2));
    const int ri0 = base0 >> 7;

    int tpc = 0, tnc = 0, fpc = 0, vc = 0;
    float ls = 0.0f;

#define DO_ELEM(aa, btj, spv, vvv)                                            \
    {                                                                         \
        const float z = (aa) + (btj);                                         \
        const int pred = (z > 0.0f) ? 1 : 0;                                  \
        tpc += ((spv) == 1) & pred;                                           \
        tnc += ((spv) == 1) & (pred ^ 1);                                     \
        fpc += ((spv) == 0) & ((vvv) == 1) & pred;                            \
        vc  += (vvv);                                                         \
        const float t = ((spv) == 1) ? z : -z;                                \
        const float u = __expf(-t);                                           \
        const float d = 1.0f + u;                                             \
        const float m = u * __builtin_amdgcn_rcpf(d);                         \
        const float fl = 0.5f * m * m * __logf(d);                            \
        ls += (vvv) ? fl : 0.0f;                                              \
    }

#pragma unroll
    for (int st = 0; st < 16; ++st) {
        const int vid = base0 + st * 256;
        const int4 sp = s4[vid];
        const int4 vv = v4[vid];
        const float av = At[ri0 + 2 * st];
        DO_ELEM(av, bt.x, sp.x, vv.x)
        DO_ELEM(av, bt.y, sp.y, vv.y)
        DO_ELEM(av, bt.z, sp.z, vv.z)
        DO_ELEM(av, bt.w, sp.w, vv.w)
    }
#undef DO_ELEM

    // wave (64-lane) reduction
    for (int off = 32; off; off >>= 1) {
        tpc += __shfl_down(tpc, off);
        tnc += __shfl_down(tnc, off);
        fpc += __shfl_down(fpc, off);
        vc  += __shfl_down(vc,  off);
        ls  += __shfl_down(ls,  off);
    }

    __shared__ int   si[4][4];
    __shared__ float sf[4];
    const int wave = tid >> 6, lane = tid & 63;
    if (lane == 0) {
        si[wave][0] = tpc; si[wave][1] = tnc; si[wave][2] = fpc; si[wave][3] = vc;
        sf[wave] = ls;
    }
    __syncthreads();
    if (tid == 0) {
        int t0 = 0, t1 = 0, t2 = 0, t3 = 0;
        float f = 0.0f;
        for (int w = 0; w < 4; ++w) {
            t0 += si[w][0]; t1 += si[w][1]; t2 += si[w][2]; t3 += si[w][3];
            f += sf[w];
        }
        float* dst = pb + blockIdx.x * 8;
        dst[0] = (float)t0;   // counts <= 16384/block: exact in float
        dst[1] = (float)t1;
        dst[2] = (float)t2;
        dst[3] = (float)t3;
        dst[4] = f;
    }
}

// ---------------------------------------------------------------------------
// Kernel 2b: k_pred — WRITE-ONLY pass. out = (At+Bt > 0) ? 1.0 : 0.0.
// Reads only tiny L2-resident At/Bt; 128 MB unidirectional write stream.
// ---------------------------------------------------------------------------
__global__ __launch_bounds__(256) void k_pred(
    const float* __restrict__ At, const float* __restrict__ Bt,
    float* __restrict__ out)
{
    const int tid = threadIdx.x;
    const int base0 = blockIdx.x * (256 * 16) + tid;   // float4-item index
    float4* o4 = (float4*)out;

    const float4 bt = *(const float4*)(Bt + ((base0 >> 16) << 9) + ((base0 & 127) << 2));
    const int ri0 = base0 >> 7;

#pragma unroll
    for (int st = 0; st < 16; ++st) {
        const int vid = base0 + st * 256;
        const float av = At[ri0 + 2 * st];
        float4 po;
        po.x = (av + bt.x > 0.0f) ? 1.0f : 0.0f;
        po.y = (av + bt.y > 0.0f) ? 1.0f : 0.0f;
        po.z = (av + bt.z > 0.0f) ? 1.0f : 0.0f;
        po.w = (av + bt.w > 0.0f) ? 1.0f : 0.0f;
        o4[vid] = po;
    }
}

// ---------------------------------------------------------------------------
// Kernel 3: unchanged.
// ---------------------------------------------------------------------------
__global__ __launch_bounds__(256) void k_fin(
    const float* __restrict__ pb, const float* __restrict__ se_part,
    const int* __restrict__ seqlen, float* __restrict__ out5)
{
    const int tid = threadIdx.x;
    long long t0 = 0, t1 = 0, t2 = 0, t3 = 0;
    float f = 0.0f, se = 0.0f;

    for (int i = tid; i < SPAN_BLOCKS; i += 256) {
        const float4 p0 = *(const float4*)(pb + i * 8);
        const float  p4 = pb[i * 8 + 4];
        t0 += (long long)p0.x; t1 += (long long)p0.y;
        t2 += (long long)p0.z; t3 += (long long)p0.w;
        f  += p4;
    }
    for (int i = tid; i < PREP_BLOCKS; i += 256) se += se_part[i];

    for (int off = 32; off; off >>= 1) {
        t0 += __shfl_down(t0, off);
        t1 += __shfl_down(t1, off);
        t2 += __shfl_down(t2, off);
        t3 += __shfl_down(t3, off);
        f  += __shfl_down(f,  off);
        se += __shfl_down(se, off);
    }

    __shared__ long long sl[4][4];
    __shared__ float sfl[4][2];
    const int wave = tid >> 6, lane = tid & 63;
    if (lane == 0) {
        sl[wave][0] = t0; sl[wave][1] = t1; sl[wave][2] = t2; sl[wave][3] = t3;
        sfl[wave][0] = f; sfl[wave][1] = se;
    }
    __syncthreads();
    if (tid == 0) {
        long long a0 = 0, a1 = 0, a2 = 0, a3 = 0;
        float af = 0.0f, ase = 0.0f;
        for (int w = 0; w < 4; ++w) {
            a0 += sl[w][0]; a1 += sl[w][1]; a2 += sl[w][2]; a3 += sl[w][3];
            af += sfl[w][0]; ase += sfl[w][1];
        }
        int ssum = 0;
        for (int i = 0; i < Bsz; ++i) ssum += seqlen[i];
        out5[0] = (float)a0;
        out5[1] = (float)a1;
        out5[2] = (float)a2;
        out5[3] = ase / (2.0f * Ll * (float)ssum);
        out5[4] = af / ((float)a3 + 1e-6f);
    }
}

extern "C" void kernel_launch(void* const* d_in, const int* in_sizes, int n_in,
                              void* d_out, int out_size, void* d_ws, size_t ws_size,
                              hipStream_t stream) {
    const float* x      = (const float*)d_in[0];
    const float* start  = (const float*)d_in[1];
    const float* end    = (const float*)d_in[2];
    const int*   span   = (const int*)d_in[3];
    const int*   val    = (const int*)d_in[4];
    const int*   seqlen = (const int*)d_in[5];
    const float* W_se   = (const float*)d_in[6];
    const float* b_se   = (const float*)d_in[7];
    const float* W_span = (const float*)d_in[8];
    const float* b_span = (const float*)d_in[9];

    float* out = (float*)d_out;

    const size_t n_at = (size_t)Bsz * Ll * Nn;    // 65536
    float* At      = (float*)d_ws;
    float* Bt      = At + n_at;
    float* se_part = Bt + n_at;
    float* pb      = se_part + PREP_BLOCKS;

    k_prep<<<PREP_BLOCKS, 256, 0, stream>>>(x, start, end, seqlen,
                                            W_se, b_se, W_span, b_span,
                                            At, Bt, se_part);

    // READ-only pass first, WRITE-only pass second (un-mixed DRAM streams)
    k_stats<<<SPAN_BLOCKS, 256, 0, stream>>>(At, Bt, span, val, pb);
    k_pred <<<SPAN_BLOCKS, 256, 0, stream>>>(At, Bt, out);

    k_fin<<<1, 256, 0, stream>>>(pb, se_part, seqlen, out + (long long)Bsz * Ll * Nn * Nn);
}

// Round 6
// 360.194 us; speedup vs baseline: 1.0603x; 1.0603x over previous
//
#include <hip/hip_runtime.h>

#define Bsz 8
#define Nn  512
#define Dd  768
#define Ll  16

#define SPAN_BLOCKS 2048
#define PREP_BLOCKS (Bsz * (Nn / 8))   // 512

typedef int   i32x4 __attribute__((ext_vector_type(4)));
typedef float f32x4 __attribute__((ext_vector_type(4)));

// ws layout (floats): At[65536] | Bt[65536] | se_part[512] | pb[SPAN_BLOCKS*8]
// pb[blk*8 + {0:tp,1:tn,2:fp,3:valc,4:span_loss_sum}]  -- plain stores, NO atomics

// ---------------------------------------------------------------------------
// Kernel 1: unchanged (proven).
// ---------------------------------------------------------------------------
__global__ __launch_bounds__(256) void k_prep(
    const float* __restrict__ x, const float* __restrict__ start,
    const float* __restrict__ end, const int* __restrict__ seqlen,
    const float* __restrict__ W_se, const float* __restrict__ b_se,
    const float* __restrict__ W_span, const float* __restrict__ b_span,
    float* __restrict__ At, float* __restrict__ Bt, float* __restrict__ se_part)
{
    __shared__ float xs[8 * Dd];        // 24 KB
    __shared__ float part[256 * 8];     // 8 KB
    __shared__ float s_se;

    const int tid = threadIdx.x;
    const int blk = blockIdx.x;         // 512 blocks: b*64 + group
    const int b   = blk >> 6;
    const int n0  = (blk & 63) * 8;

    if (tid == 0) s_se = 0.0f;

    const float4* xsrc = (const float4*)(x + (size_t)(b * Nn + n0) * Dd);
    float4* xd = (float4*)xs;
    for (int i = tid; i < 8 * Dd / 4; i += 256) xd[i] = xsrc[i];
    __syncthreads();

    const int c = tid & 63;   // column 0..63
    const int q = tid >> 6;   // k-quarter 0..3

    float a8[8];
#pragma unroll
    for (int r = 0; r < 8; ++r) a8[r] = 0.0f;

    const float* w;
    int stride;
    if (c < 32)       { w = W_se + c;                    stride = 32; }
    else if (c < 48)  { w = W_span + (c - 32);           stride = 16; }
    else              { w = W_span + Dd * 16 + (c - 48); stride = 16; }

    const int k0 = q * 192;
#pragma unroll 4
    for (int k = k0; k < k0 + 192; ++k) {
        const float wv = w[(size_t)k * stride];
#pragma unroll
        for (int r = 0; r < 8; ++r) a8[r] += xs[r * Dd + k] * wv;
    }
#pragma unroll
    for (int r = 0; r < 8; ++r) part[tid * 8 + r] = a8[r];
    __syncthreads();

    if (tid < 64) {
        float z[8];
#pragma unroll
        for (int r = 0; r < 8; ++r)
            z[r] = part[c * 8 + r] + part[(c + 64) * 8 + r] +
                   part[(c + 128) * 8 + r] + part[(c + 192) * 8 + r];

        if (c < 32) {
            const int sl = seqlen[b];
            float lsum = 0.0f;
            const float bse = b_se[c];
#pragma unroll
            for (int r = 0; r < 8; ++r) {
                const int n = n0 + r;
                const float zz = z[r] + bse;
                const float p = 1.0f / (1.0f + __expf(-zz));
                const float y = (c < 16) ? start[(b * Ll + c) * Nn + n]
                                         : end[(b * Ll + (c - 16)) * Nn + n];
                const float fl = (y == 1.0f)
                    ? (-0.5f * (1.0f - p) * (1.0f - p) * __logf(p))
                    : (-0.5f * p * p * __logf(1.0f - p));
                if (n < sl) lsum += fl;
            }
            atomicAdd(&s_se, lsum);
        } else if (c < 48) {
            const int l = c - 32;
            const float bsp = b_span[l];
#pragma unroll
            for (int r = 0; r < 8; ++r)
                At[(b * Ll + l) * Nn + n0 + r] = z[r] + bsp;  // bias folded in
        } else {
            const int l = c - 48;
#pragma unroll
            for (int r = 0; r < 8; ++r)
                Bt[(b * Ll + l) * Nn + n0 + r] = z[r];
        }
    }
    __syncthreads();
    if (tid == 0) se_part[blk] = s_se;
}

// ---------------------------------------------------------------------------
// Kernel 2: combined pass (round-0 structure — measured best; write stream
// overlaps nearly free per round-5 split: k_pred was 27us at 4.8 TB/s).
//
// NEW: span/val loads are NON-TEMPORAL. These arrays are read exactly once
// per run; their only L3 "reuse" is cross-iteration residency (FETCH=133MB
// of 256MB demand), and round-5 showed the hit/miss-interleaved read stream
// crawls at 2.44 TB/s while a pure stream does 3.15+ (m13). nt stops L3
// allocation -> all 256MB streams from HBM. Tell: FETCH 133 -> ~256 MB.
//
// focal closed form: z = logit; t = (span==1)? z : -z; u=e^{-t}; d=1+u;
//   focal = 0.5 * (u/d)^2 * log d
// ---------------------------------------------------------------------------
__global__ __launch_bounds__(256) void k_span(
    const float* __restrict__ At, const float* __restrict__ Bt,
    const int* __restrict__ span, const int* __restrict__ val,
    float* __restrict__ out, float* __restrict__ pb)
{
    const int tid = threadIdx.x;
    const int base0 = blockIdx.x * (256 * 16) + tid;   // float4-item index

    const i32x4* s4 = (const i32x4*)span;
    const i32x4* v4 = (const i32x4*)val;
    float4*      o4 = (float4*)out;

    int tpc = 0, tnc = 0, fpc = 0, vc = 0;
    float ls = 0.0f;

#define DO_ELEM(aa, btj, spv, vvv, pout)                                      \
    {                                                                         \
        const float z = (aa) + (btj);                                         \
        const int pred = (z > 0.0f) ? 1 : 0;                                  \
        (pout) = pred ? 1.0f : 0.0f;                                          \
        tpc += ((spv) == 1) & pred;                                           \
        tnc += ((spv) == 1) & (pred ^ 1);                                     \
        fpc += ((spv) == 0) & ((vvv) == 1) & pred;                            \
        vc  += (vvv);                                                         \
        const float t = ((spv) == 1) ? z : -z;                                \
        const float u = __expf(-t);                                           \
        const float d = 1.0f + u;                                             \
        const float m = u * __builtin_amdgcn_rcpf(d);                         \
        const float fl = 0.5f * m * m * __logf(d);                            \
        ls += (vvv) ? fl : 0.0f;                                              \
    }

#pragma unroll
    for (int bat = 0; bat < 4; ++bat) {
        int   vid[4];
        i32x4 sp[4], vv[4];
        float4 bt[4];
        float  av[4];
#pragma unroll
        for (int k = 0; k < 4; ++k) {
            vid[k] = base0 + bat * 1024 + k * 256;
            sp[k]  = __builtin_nontemporal_load(s4 + vid[k]);
            vv[k]  = __builtin_nontemporal_load(v4 + vid[k]);
            const int ri = vid[k] >> 7;                  // (b*L+l)*N + i
            av[k]  = At[ri];
            bt[k]  = *(const float4*)(Bt + ((ri >> 9) << 9) + ((vid[k] & 127) << 2));
        }
#pragma unroll
        for (int k = 0; k < 4; ++k) {
            float4 po;
            DO_ELEM(av[k], bt[k].x, sp[k].x, vv[k].x, po.x)
            DO_ELEM(av[k], bt[k].y, sp[k].y, vv[k].y, po.y)
            DO_ELEM(av[k], bt[k].z, sp[k].z, vv[k].z, po.z)
            DO_ELEM(av[k], bt[k].w, sp[k].w, vv[k].w, po.w)
            o4[vid[k]] = po;
        }
    }
#undef DO_ELEM

    // wave (64-lane) reduction
    for (int off = 32; off; off >>= 1) {
        tpc += __shfl_down(tpc, off);
        tnc += __shfl_down(tnc, off);
        fpc += __shfl_down(fpc, off);
        vc  += __shfl_down(vc,  off);
        ls  += __shfl_down(ls,  off);
    }

    __shared__ int   si[4][4];
    __shared__ float sf[4];
    const int wave = tid >> 6, lane = tid & 63;
    if (lane == 0) {
        si[wave][0] = tpc; si[wave][1] = tnc; si[wave][2] = fpc; si[wave][3] = vc;
        sf[wave] = ls;
    }
    __syncthreads();
    if (tid == 0) {
        int t0 = 0, t1 = 0, t2 = 0, t3 = 0;
        float f = 0.0f;
        for (int w = 0; w < 4; ++w) {
            t0 += si[w][0]; t1 += si[w][1]; t2 += si[w][2]; t3 += si[w][3];
            f += sf[w];
        }
        float* dst = pb + blockIdx.x * 8;
        dst[0] = (float)t0;   // counts <= 16384/block: exact in float
        dst[1] = (float)t1;
        dst[2] = (float)t2;
        dst[3] = (float)t3;
        dst[4] = f;
    }
}

// ---------------------------------------------------------------------------
// Kernel 3: unchanged.
// ---------------------------------------------------------------------------
__global__ __launch_bounds__(256) void k_fin(
    const float* __restrict__ pb, const float* __restrict__ se_part,
    const int* __restrict__ seqlen, float* __restrict__ out5)
{
    const int tid = threadIdx.x;
    long long t0 = 0, t1 = 0, t2 = 0, t3 = 0;
    float f = 0.0f, se = 0.0f;

    for (int i = tid; i < SPAN_BLOCKS; i += 256) {
        const float4 p0 = *(const float4*)(pb + i * 8);
        const float  p4 = pb[i * 8 + 4];
        t0 += (long long)p0.x; t1 += (long long)p0.y;
        t2 += (long long)p0.z; t3 += (long long)p0.w;
        f  += p4;
    }
    for (int i = tid; i < PREP_BLOCKS; i += 256) se += se_part[i];

    for (int off = 32; off; off >>= 1) {
        t0 += __shfl_down(t0, off);
        t1 += __shfl_down(t1, off);
        t2 += __shfl_down(t2, off);
        t3 += __shfl_down(t3, off);
        f  += __shfl_down(f,  off);
        se += __shfl_down(se, off);
    }

    __shared__ long long sl[4][4];
    __shared__ float sfl[4][2];
    const int wave = tid >> 6, lane = tid & 63;
    if (lane == 0) {
        sl[wave][0] = t0; sl[wave][1] = t1; sl[wave][2] = t2; sl[wave][3] = t3;
        sfl[wave][0] = f; sfl[wave][1] = se;
    }
    __syncthreads();
    if (tid == 0) {
        long long a0 = 0, a1 = 0, a2 = 0, a3 = 0;
        float af = 0.0f, ase = 0.0f;
        for (int w = 0; w < 4; ++w) {
            a0 += sl[w][0]; a1 += sl[w][1]; a2 += sl[w][2]; a3 += sl[w][3];
            af += sfl[w][0]; ase += sfl[w][1];
        }
        int ssum = 0;
        for (int i = 0; i < Bsz; ++i) ssum += seqlen[i];
        out5[0] = (float)a0;
        out5[1] = (float)a1;
        out5[2] = (float)a2;
        out5[3] = ase / (2.0f * Ll * (float)ssum);
        out5[4] = af / ((float)a3 + 1e-6f);
    }
}

extern "C" void kernel_launch(void* const* d_in, const int* in_sizes, int n_in,
                              void* d_out, int out_size, void* d_ws, size_t ws_size,
                              hipStream_t stream) {
    const float* x      = (const float*)d_in[0];
    const float* start  = (const float*)d_in[1];
    const float* end    = (const float*)d_in[2];
    const int*   span   = (const int*)d_in[3];
    const int*   val    = (const int*)d_in[4];
    const int*   seqlen = (const int*)d_in[5];
    const float* W_se   = (const float*)d_in[6];
    const float* b_se   = (const float*)d_in[7];
    const float* W_span = (const float*)d_in[8];
    const float* b_span = (const float*)d_in[9];

    float* out = (float*)d_out;

    const size_t n_at = (size_t)Bsz * Ll * Nn;    // 65536
    float* At      = (float*)d_ws;
    float* Bt      = At + n_at;
    float* se_part = Bt + n_at;
    float* pb      = se_part + PREP_BLOCKS;

    k_prep<<<PREP_BLOCKS, 256, 0, stream>>>(x, start, end, seqlen,
                                            W_se, b_se, W_span, b_span,
                                            At, Bt, se_part);

    k_span<<<SPAN_BLOCKS, 256, 0, stream>>>(At, Bt, span, val, out, pb);

    k_fin<<<1, 256, 0, stream>>>(pb, se_part, seqlen, out + (long long)Bsz * Ll * Nn * Nn);
}

// Round 8
// 354.728 us; speedup vs baseline: 1.0766x; 1.0154x over previous
//
#include <hip/hip_runtime.h>

#define Bsz 8
#define Nn  512
#define Dd  768
#define Ll  16

#define SPAN_BLOCKS 2048
#define PREP_BLOCKS (Bsz * (Nn / 8))   // 512

typedef int   i32x4 __attribute__((ext_vector_type(4)));
typedef float f32x4 __attribute__((ext_vector_type(4)));

// ws layout (floats): At[65536] | Bt[65536] | se_part[512] | pb[SPAN_BLOCKS*8]
// pb[blk*8 + {0:tp,1:tn,2:fp,3:valc,4:span_loss_sum}]  -- plain stores, NO atomics

// ---------------------------------------------------------------------------
// Kernel 1: unchanged (proven).
// ---------------------------------------------------------------------------
__global__ __launch_bounds__(256) void k_prep(
    const float* __restrict__ x, const float* __restrict__ start,
    const float* __restrict__ end, const int* __restrict__ seqlen,
    const float* __restrict__ W_se, const float* __restrict__ b_se,
    const float* __restrict__ W_span, const float* __restrict__ b_span,
    float* __restrict__ At, float* __restrict__ Bt, float* __restrict__ se_part)
{
    __shared__ float xs[8 * Dd];        // 24 KB
    __shared__ float part[256 * 8];     // 8 KB
    __shared__ float s_se;

    const int tid = threadIdx.x;
    const int blk = blockIdx.x;         // 512 blocks: b*64 + group
    const int b   = blk >> 6;
    const int n0  = (blk & 63) * 8;

    if (tid == 0) s_se = 0.0f;

    const float4* xsrc = (const float4*)(x + (size_t)(b * Nn + n0) * Dd);
    float4* xd = (float4*)xs;
    for (int i = tid; i < 8 * Dd / 4; i += 256) xd[i] = xsrc[i];
    __syncthreads();

    const int c = tid & 63;   // column 0..63
    const int q = tid >> 6;   // k-quarter 0..3

    float a8[8];
#pragma unroll
    for (int r = 0; r < 8; ++r) a8[r] = 0.0f;

    const float* w;
    int stride;
    if (c < 32)       { w = W_se + c;                    stride = 32; }
    else if (c < 48)  { w = W_span + (c - 32);           stride = 16; }
    else              { w = W_span + Dd * 16 + (c - 48); stride = 16; }

    const int k0 = q * 192;
#pragma unroll 4
    for (int k = k0; k < k0 + 192; ++k) {
        const float wv = w[(size_t)k * stride];
#pragma unroll
        for (int r = 0; r < 8; ++r) a8[r] += xs[r * Dd + k] * wv;
    }
#pragma unroll
    for (int r = 0; r < 8; ++r) part[tid * 8 + r] = a8[r];
    __syncthreads();

    if (tid < 64) {
        float z[8];
#pragma unroll
        for (int r = 0; r < 8; ++r)
            z[r] = part[c * 8 + r] + part[(c + 64) * 8 + r] +
                   part[(c + 128) * 8 + r] + part[(c + 192) * 8 + r];

        if (c < 32) {
            const int sl = seqlen[b];
            float lsum = 0.0f;
            const float bse = b_se[c];
#pragma unroll
            for (int r = 0; r < 8; ++r) {
                const int n = n0 + r;
                const float zz = z[r] + bse;
                const float p = 1.0f / (1.0f + __expf(-zz));
                const float y = (c < 16) ? start[(b * Ll + c) * Nn + n]
                                         : end[(b * Ll + (c - 16)) * Nn + n];
                const float fl = (y == 1.0f)
                    ? (-0.5f * (1.0f - p) * (1.0f - p) * __logf(p))
                    : (-0.5f * p * p * __logf(1.0f - p));
                if (n < sl) lsum += fl;
            }
            atomicAdd(&s_se, lsum);
        } else if (c < 48) {
            const int l = c - 32;
            const float bsp = b_span[l];
#pragma unroll
            for (int r = 0; r < 8; ++r)
                At[(b * Ll + l) * Nn + n0 + r] = z[r] + bsp;  // bias folded in
        } else {
            const int l = c - 48;
#pragma unroll
            for (int r = 0; r < 8; ++r)
                Bt[(b * Ll + l) * Nn + n0 + r] = z[r];
        }
    }
    __syncthreads();
    if (tid == 0) se_part[blk] = s_se;
}

// ---------------------------------------------------------------------------
// Kernel 2: combined pass. Round-6 proved NT LOADS on span/val = -28%
// (115 -> 82.5us, hbm 2.3 -> 3.3 TB/s). FETCH stayed ~132MB: the harness's
// per-iteration input restore keeps span/val half-resident in L3 and nt
// loads still consume those hits — the win came from not thrashing the
// cache hierarchy with the streaming reads.
//
// THIS round (resubmit — round 7 was an infra failure, experiment never ran):
// NT STORES on out as well (single-variable A/B). out is the last
// cache-allocating stream; its 128MB/iter write-allocate is the only thing
// left evicting the restore-resident input lines. Round-1's nt-store
// regression was measured in the pre-nt-load regime — re-testing in the new
// regime. Tells: FETCH 132 -> <90MB and k_span 82 -> ~70us if right;
// k_span >= 90us if the nt store path is just slow (then revert + declare).
//
// focal closed form: z = logit; t = (span==1)? z : -z; u=e^{-t}; d=1+u;
//   focal = 0.5 * (u/d)^2 * log d
// ---------------------------------------------------------------------------
__global__ __launch_bounds__(256) void k_span(
    const float* __restrict__ At, const float* __restrict__ Bt,
    const int* __restrict__ span, const int* __restrict__ val,
    float* __restrict__ out, float* __restrict__ pb)
{
    const int tid = threadIdx.x;
    const int base0 = blockIdx.x * (256 * 16) + tid;   // float4-item index

    const i32x4* s4 = (const i32x4*)span;
    const i32x4* v4 = (const i32x4*)val;
    f32x4*       o4 = (f32x4*)out;

    int tpc = 0, tnc = 0, fpc = 0, vc = 0;
    float ls = 0.0f;

#define DO_ELEM(aa, btj, spv, vvv, pout)                                      \
    {                                                                         \
        const float z = (aa) + (btj);                                         \
        const int pred = (z > 0.0f) ? 1 : 0;                                  \
        (pout) = pred ? 1.0f : 0.0f;                                          \
        tpc += ((spv) == 1) & pred;                                           \
        tnc += ((spv) == 1) & (pred ^ 1);                                     \
        fpc += ((spv) == 0) & ((vvv) == 1) & pred;                            \
        vc  += (vvv);                                                         \
        const float t = ((spv) == 1) ? z : -z;                                \
        const float u = __expf(-t);                                           \
        const float d = 1.0f + u;                                             \
        const float m = u * __builtin_amdgcn_rcpf(d);                         \
        const float fl = 0.5f * m * m * __logf(d);                            \
        ls += (vvv) ? fl : 0.0f;                                              \
    }

#pragma unroll
    for (int bat = 0; bat < 4; ++bat) {
        int   vid[4];
        i32x4 sp[4], vv[4];
        float4 bt[4];
        float  av[4];
#pragma unroll
        for (int k = 0; k < 4; ++k) {
            vid[k] = base0 + bat * 1024 + k * 256;
            sp[k]  = __builtin_nontemporal_load(s4 + vid[k]);
            vv[k]  = __builtin_nontemporal_load(v4 + vid[k]);
            const int ri = vid[k] >> 7;                  // (b*L+l)*N + i
            av[k]  = At[ri];
            bt[k]  = *(const float4*)(Bt + ((ri >> 9) << 9) + ((vid[k] & 127) << 2));
        }
#pragma unroll
        for (int k = 0; k < 4; ++k) {
            f32x4 po;
            DO_ELEM(av[k], bt[k].x, sp[k].x, vv[k].x, po.x)
            DO_ELEM(av[k], bt[k].y, sp[k].y, vv[k].y, po.y)
            DO_ELEM(av[k], bt[k].z, sp[k].z, vv[k].z, po.z)
            DO_ELEM(av[k], bt[k].w, sp[k].w, vv[k].w, po.w)
            __builtin_nontemporal_store(po, o4 + vid[k]);
        }
    }
#undef DO_ELEM

    // wave (64-lane) reduction
    for (int off = 32; off; off >>= 1) {
        tpc += __shfl_down(tpc, off);
        tnc += __shfl_down(tnc, off);
        fpc += __shfl_down(fpc, off);
        vc  += __shfl_down(vc,  off);
        ls  += __shfl_down(ls,  off);
    }

    __shared__ int   si[4][4];
    __shared__ float sf[4];
    const int wave = tid >> 6, lane = tid & 63;
    if (lane == 0) {
        si[wave][0] = tpc; si[wave][1] = tnc; si[wave][2] = fpc; si[wave][3] = vc;
        sf[wave] = ls;
    }
    __syncthreads();
    if (tid == 0) {
        int t0 = 0, t1 = 0, t2 = 0, t3 = 0;
        float f = 0.0f;
        for (int w = 0; w < 4; ++w) {
            t0 += si[w][0]; t1 += si[w][1]; t2 += si[w][2]; t3 += si[w][3];
            f += sf[w];
        }
        float* dst = pb + blockIdx.x * 8;
        dst[0] = (float)t0;   // counts <= 16384/block: exact in float
        dst[1] = (float)t1;
        dst[2] = (float)t2;
        dst[3] = (float)t3;
        dst[4] = f;
    }
}

// ---------------------------------------------------------------------------
// Kernel 3: unchanged.
// ---------------------------------------------------------------------------
__global__ __launch_bounds__(256) void k_fin(
    const float* __restrict__ pb, const float* __restrict__ se_part,
    const int* __restrict__ seqlen, float* __restrict__ out5)
{
    const int tid = threadIdx.x;
    long long t0 = 0, t1 = 0, t2 = 0, t3 = 0;
    float f = 0.0f, se = 0.0f;

    for (int i = tid; i < SPAN_BLOCKS; i += 256) {
        const float4 p0 = *(const float4*)(pb + i * 8);
        const float  p4 = pb[i * 8 + 4];
        t0 += (long long)p0.x; t1 += (long long)p0.y;
        t2 += (long long)p0.z; t3 += (long long)p0.w;
        f  += p4;
    }
    for (int i = tid; i < PREP_BLOCKS; i += 256) se += se_part[i];

    for (int off = 32; off; off >>= 1) {
        t0 += __shfl_down(t0, off);
        t1 += __shfl_down(t1, off);
        t2 += __shfl_down(t2, off);
        t3 += __shfl_down(t3, off);
        f  += __shfl_down(f,  off);
        se += __shfl_down(se, off);
    }

    __shared__ long long sl[4][4];
    __shared__ float sfl[4][2];
    const int wave = tid >> 6, lane = tid & 63;
    if (lane == 0) {
        sl[wave][0] = t0; sl[wave][1] = t1; sl[wave][2] = t2; sl[wave][3] = t3;
        sfl[wave][0] = f; sfl[wave][1] = se;
    }
    __syncthreads();
    if (tid == 0) {
        long long a0 = 0, a1 = 0, a2 = 0, a3 = 0;
        float af = 0.0f, ase = 0.0f;
        for (int w = 0; w < 4; ++w) {
            a0 += sl[w][0]; a1 += sl[w][1]; a2 += sl[w][2]; a3 += sl[w][3];
            af += sfl[w][0]; ase += sfl[w][1];
        }
        int ssum = 0;
        for (int i = 0; i < Bsz; ++i) ssum += seqlen[i];
        out5[0] = (float)a0;
        out5[1] = (float)a1;
        out5[2] = (float)a2;
        out5[3] = ase / (2.0f * Ll * (float)ssum);
        out5[4] = af / ((float)a3 + 1e-6f);
    }
}

extern "C" void kernel_launch(void* const* d_in, const int* in_sizes, int n_in,
                              void* d_out, int out_size, void* d_ws, size_t ws_size,
                              hipStream_t stream) {
    const float* x      = (const float*)d_in[0];
    const float* start  = (const float*)d_in[1];
    const float* end    = (const float*)d_in[2];
    const int*   span   = (const int*)d_in[3];
    const int*   val    = (const int*)d_in[4];
    const int*   seqlen = (const int*)d_in[5];
    const float* W_se   = (const float*)d_in[6];
    const float* b_se   = (const float*)d_in[7];
    const float* W_span = (const float*)d_in[8];
    const float* b_span = (const float*)d_in[9];

    float* out = (float*)d_out;

    const size_t n_at = (size_t)Bsz * Ll * Nn;    // 65536
    float* At      = (float*)d_ws;
    float* Bt      = At + n_at;
    float* se_part = Bt + n_at;
    float* pb      = se_part + PREP_BLOCKS;

    k_prep<<<PREP_BLOCKS, 256, 0, stream>>>(x, start, end, seqlen,
                                            W_se, b_se, W_span, b_span,
                                            At, Bt, se_part);

    k_span<<<SPAN_BLOCKS, 256, 0, stream>>>(At, Bt, span, val, out, pb);

    k_fin<<<1, 256, 0, stream>>>(pb, se_part, seqlen, out + (long long)Bsz * Ll * Nn * Nn);
}